// Round 1
// baseline (1436.285 us; speedup 1.0000x reference)
//
#include <hip/hip_runtime.h>

#define NN 100000
#define NE 1600000

// ---------------- CSR build ----------------

__global__ __launch_bounds__(256) void k_hist(const int* __restrict__ dst,
                                              int* __restrict__ deg) {
    int e = blockIdx.x * 256 + threadIdx.x;
    if (e < NE) atomicAdd(&deg[dst[e]], 1);
}

__global__ __launch_bounds__(1024) void k_scan(const int* __restrict__ deg,
                                               int* __restrict__ row_off,
                                               int* __restrict__ cursor) {
    __shared__ int sums[1024];
    int tid = threadIdx.x;
    const int CH = (NN + 1023) / 1024;   // 98
    int lo = tid * CH;
    int hi = lo + CH;
    if (lo > NN) lo = NN;
    if (hi > NN) hi = NN;
    int s = 0;
    for (int i = lo; i < hi; ++i) s += deg[i];
    sums[tid] = s;
    __syncthreads();
    for (int off = 1; off < 1024; off <<= 1) {
        int v = 0;
        if (tid >= off) v = sums[tid - off];
        __syncthreads();
        if (tid >= off) sums[tid] += v;
        __syncthreads();
    }
    int base = (tid == 0) ? 0 : sums[tid - 1];
    for (int i = lo; i < hi; ++i) {
        row_off[i] = base;
        cursor[i] = base;
        base += deg[i];
    }
    if (tid == 1023) row_off[NN] = base;   // == NE
}

__global__ __launch_bounds__(256) void k_fill(const int* __restrict__ src,
                                              const int* __restrict__ dst,
                                              int* __restrict__ cursor,
                                              int* __restrict__ csr) {
    int e = blockIdx.x * 256 + threadIdx.x;
    if (e < NE) {
        int p = atomicAdd(&cursor[dst[e]], 1);
        csr[p] = src[e];
    }
}

// ---------------- fused dual GEMM:  Y = H @ Wl,  Z = H @ Wr ----------------
// H: [NN,128] fp32.  Wl/Wr: [128,NOUT].  Y/Z: [NN,NOUT].
// Block: 256 threads, BM=32 rows, full N2=2*NOUT cols, K chunked by 32.

template <int NOUT>
__global__ __launch_bounds__(256) void k_gemm(const float* __restrict__ H,
                                              const float* __restrict__ Wl,
                                              const float* __restrict__ Wr,
                                              float* __restrict__ Y,
                                              float* __restrict__ Z) {
    constexpr int N2 = 2 * NOUT;        // 256 or 128
    constexpr int BM = 32;
    constexpr int BK = 32;
    constexpr int CG = N2 / 8;          // col groups: 32 or 16
    constexpr int RG = 256 / CG;        // row groups: 8 or 16
    constexpr int RPT = BM / RG;        // rows per thread: 4 or 2

    __shared__ float At[BK][BM + 1];    // transposed A tile (pad to dodge conflicts)
    __shared__ float Wt[BK][N2];

    int tid = threadIdx.x;
    int row0 = blockIdx.x * BM;         // NN % 32 == 0, no bounds needed
    int tx = tid % CG;                  // col group -> cols tx*8 .. tx*8+7
    int ty = tid / CG;                  // row group -> rows ty*RPT .. +RPT-1

    float acc[RPT][8];
#pragma unroll
    for (int r = 0; r < RPT; ++r)
#pragma unroll
        for (int c = 0; c < 8; ++c) acc[r][c] = 0.f;

    int ar = tid / 8;                   // 0..31 row within tile (A staging)
    int ac = (tid % 8) * 4;             // 0..28 k-col within tile

    for (int k0 = 0; k0 < 128; k0 += BK) {
        // stage A (32x32, transposed)
        float4 av = *(const float4*)&H[(size_t)(row0 + ar) * 128 + k0 + ac];
        At[ac + 0][ar] = av.x;
        At[ac + 1][ar] = av.y;
        At[ac + 2][ar] = av.z;
        At[ac + 3][ar] = av.w;
        // stage W (32 x N2): combined [Wl | Wr]
        constexpr int NF4 = (BK * N2) / (256 * 4);   // 8 or 4 float4 per thread
#pragma unroll
        for (int p = 0; p < NF4; ++p) {
            int idx = (p * 256 + tid) * 4;           // float index into [BK][N2]
            int k = idx / N2;
            int j = idx % N2;
            float4 wv;
            if (j < NOUT) wv = *(const float4*)&Wl[(size_t)(k0 + k) * NOUT + j];
            else          wv = *(const float4*)&Wr[(size_t)(k0 + k) * NOUT + (j - NOUT)];
            *(float4*)&Wt[k][j] = wv;
        }
        __syncthreads();

#pragma unroll
        for (int kk = 0; kk < BK; ++kk) {
            float a[RPT];
#pragma unroll
            for (int r = 0; r < RPT; ++r) a[r] = At[kk][ty * RPT + r];
            float w[8];
#pragma unroll
            for (int c = 0; c < 8; ++c) w[c] = Wt[kk][tx * 8 + c];
#pragma unroll
            for (int r = 0; r < RPT; ++r)
#pragma unroll
                for (int c = 0; c < 8; ++c) acc[r][c] += a[r] * w[c];
        }
        __syncthreads();
    }

    // epilogue: cols tx*8..+7 lie entirely in Y-half or Z-half
    int j0 = tx * 8;
#pragma unroll
    for (int r = 0; r < RPT; ++r) {
        int row = row0 + ty * RPT + r;
        float* dstp = (j0 < NOUT) ? &Y[(size_t)row * NOUT + j0]
                                  : &Z[(size_t)row * NOUT + (j0 - NOUT)];
        float4 v0 = {acc[r][0], acc[r][1], acc[r][2], acc[r][3]};
        float4 v1 = {acc[r][4], acc[r][5], acc[r][6], acc[r][7]};
        *(float4*)&dstp[0] = v0;
        *(float4*)&dstp[4] = v1;
    }
}

// ---------------- aggregation:  out = mean_{nbr} Y[nbr] + Z[n] + b  (opt LeakyReLU) ----

template <int NOUT, bool RELU>
__global__ __launch_bounds__(256) void k_agg(const float* __restrict__ Y,
                                             const float* __restrict__ Z,
                                             const int* __restrict__ row_off,
                                             const int* __restrict__ csr,
                                             const float* __restrict__ b,
                                             float* __restrict__ out) {
    int wave = threadIdx.x >> 6;
    int lane = threadIdx.x & 63;
    int n = blockIdx.x * 4 + wave;
    if (n >= NN) return;
    int beg = row_off[n];
    int end = row_off[n + 1];
    float inv = (end > beg) ? 1.0f / (float)(end - beg) : 0.0f;

    if (NOUT == 128) {
        float2 acc = {0.f, 0.f};
        for (int e = beg; e < end; ++e) {
            int s = csr[e];
            float2 v = *(const float2*)&Y[(size_t)s * 128 + lane * 2];
            acc.x += v.x;
            acc.y += v.y;
        }
        float2 z = *(const float2*)&Z[(size_t)n * 128 + lane * 2];
        float2 bb = *(const float2*)&b[lane * 2];
        float ox = acc.x * inv + z.x + bb.x;
        float oy = acc.y * inv + z.y + bb.y;
        if (RELU) {
            ox = ox > 0.f ? ox : 0.1f * ox;
            oy = oy > 0.f ? oy : 0.1f * oy;
        }
        *(float2*)&out[(size_t)n * 128 + lane * 2] = make_float2(ox, oy);
    } else {
        float acc = 0.f;
        for (int e = beg; e < end; ++e) {
            int s = csr[e];
            acc += Y[(size_t)s * 64 + lane];
        }
        float o = acc * inv + Z[(size_t)n * 64 + lane] + b[lane];
        if (RELU) o = o > 0.f ? o : 0.1f * o;
        out[(size_t)n * 64 + lane] = o;
    }
}

// ---------------- launch ----------------

extern "C" void kernel_launch(void* const* d_in, const int* in_sizes, int n_in,
                              void* d_out, int out_size, void* d_ws, size_t ws_size,
                              hipStream_t stream) {
    const float* x        = (const float*)d_in[0];
    const int*   ei       = (const int*)d_in[1];
    const float* Wl_stack = (const float*)d_in[2];
    const float* Wr_stack = (const float*)d_in[3];
    const float* b_stack  = (const float*)d_in[4];
    const float* Wl_out   = (const float*)d_in[5];
    const float* Wr_out   = (const float*)d_in[6];
    const float* b_out    = (const float*)d_in[7];
    float* out = (float*)d_out;

    // workspace layout: float buffers first (16B alignment), ints after
    float* hbuf = (float*)d_ws;                       // [NN,128]
    float* Y    = hbuf + (size_t)NN * 128;            // [NN,128]
    float* Z    = Y + (size_t)NN * 128;               // [NN,128]
    int* deg     = (int*)(Z + (size_t)NN * 128);      // [NN]
    int* row_off = deg + NN;                          // [NN+1]
    int* cursor  = row_off + NN + 1;                  // [NN]
    int* csr     = cursor + NN;                       // [NE]

    const int* src = ei;
    const int* dst = ei + NE;

    // CSR build (per call; graph-capture safe)
    hipMemsetAsync(deg, 0, NN * sizeof(int), stream);
    k_hist<<<(NE + 255) / 256, 256, 0, stream>>>(dst, deg);
    k_scan<<<1, 1024, 0, stream>>>(deg, row_off, cursor);
    k_fill<<<(NE + 255) / 256, 256, 0, stream>>>(src, dst, cursor, csr);

    const float* hin = x;
    for (int l = 0; l < 3; ++l) {
        k_gemm<128><<<NN / 32, 256, 0, stream>>>(hin, Wl_stack + l * 16384,
                                                 Wr_stack + l * 16384, Y, Z);
        k_agg<128, true><<<NN / 4, 256, 0, stream>>>(Y, Z, row_off, csr,
                                                     b_stack + l * 128, hbuf);
        hin = hbuf;
    }
    k_gemm<64><<<NN / 32, 256, 0, stream>>>(hin, Wl_out, Wr_out, Y, Z);
    k_agg<64, false><<<NN / 4, 256, 0, stream>>>(Y, Z, row_off, csr, b_out, out);
}

// Round 3
// 1212.280 us; speedup vs baseline: 1.1848x; 1.1848x over previous
//
#include <hip/hip_runtime.h>

#define NN 100000
#define NE 1600000
#define SCAN_B ((NN + 255) / 256)   // 391 blocks

// ---------------- CSR build ----------------

__global__ __launch_bounds__(256) void k_hist(const int* __restrict__ dst,
                                              int* __restrict__ deg) {
    int e = blockIdx.x * 256 + threadIdx.x;
    if (e < NE) atomicAdd(&deg[dst[e]], 1);
}

// per-block inclusive scan -> local exclusive prefix + block sums
__global__ __launch_bounds__(256) void k_scan1(const int* __restrict__ deg,
                                               int* __restrict__ local,
                                               int* __restrict__ bsum) {
    __shared__ int s[256];
    int tid = threadIdx.x;
    int i = blockIdx.x * 256 + tid;
    int v = (i < NN) ? deg[i] : 0;
    s[tid] = v;
    __syncthreads();
#pragma unroll
    for (int off = 1; off < 256; off <<= 1) {
        int t = (tid >= off) ? s[tid - off] : 0;
        __syncthreads();
        if (tid >= off) s[tid] += t;
        __syncthreads();
    }
    if (i < NN) local[i] = s[tid] - v;          // exclusive
    if (tid == 255) bsum[blockIdx.x] = s[255];  // block total
}

// scan the block sums (SCAN_B = 391 <= 512)
__global__ __launch_bounds__(512) void k_scan2(int* __restrict__ bsum,
                                               int* __restrict__ bpre) {
    __shared__ int s[512];
    int tid = threadIdx.x;
    int v = (tid < SCAN_B) ? bsum[tid] : 0;
    s[tid] = v;
    __syncthreads();
#pragma unroll
    for (int off = 1; off < 512; off <<= 1) {
        int t = (tid >= off) ? s[tid - off] : 0;
        __syncthreads();
        if (tid >= off) s[tid] += t;
        __syncthreads();
    }
    if (tid < SCAN_B) bpre[tid] = s[tid] - v;   // exclusive
}

// add block offset, emit row_off + cursor
__global__ __launch_bounds__(256) void k_scan3(const int* __restrict__ local,
                                               const int* __restrict__ bpre,
                                               int* __restrict__ row_off,
                                               int* __restrict__ cursor) {
    int i = blockIdx.x * 256 + threadIdx.x;
    if (i < NN) {
        int r = local[i] + bpre[blockIdx.x];
        row_off[i] = r;
        cursor[i] = r;
    }
    if (i == 0) row_off[NN] = NE;               // all dst < NN, total is exact
}

__global__ __launch_bounds__(256) void k_fill(const int* __restrict__ src,
                                              const int* __restrict__ dst,
                                              int* __restrict__ cursor,
                                              int* __restrict__ csr) {
    int e = blockIdx.x * 256 + threadIdx.x;
    if (e < NE) {
        int p = atomicAdd(&cursor[dst[e]], 1);
        csr[p] = src[e];
    }
}

// ---------------- fused dual GEMM:  Y = H @ Wl,  Z = H @ Wr ----------------
// H: [NN,128] fp32.  Wl/Wr: [128,NOUT].  Y/Z: [NN,NOUT].
// Block: 256 threads, BM=32 rows, full N2=2*NOUT cols, K chunked by 32.

template <int NOUT>
__global__ __launch_bounds__(256) void k_gemm(const float* __restrict__ H,
                                              const float* __restrict__ Wl,
                                              const float* __restrict__ Wr,
                                              float* __restrict__ Y,
                                              float* __restrict__ Z) {
    constexpr int N2 = 2 * NOUT;        // 256 or 128
    constexpr int BM = 32;
    constexpr int BK = 32;
    constexpr int CG = N2 / 8;          // col groups: 32 or 16
    constexpr int RG = 256 / CG;        // row groups: 8 or 16
    constexpr int RPT = BM / RG;        // rows per thread: 4 or 2

    __shared__ float At[BK][BM + 1];    // transposed A tile (pad to dodge conflicts)
    __shared__ float Wt[BK][N2];

    int tid = threadIdx.x;
    int row0 = blockIdx.x * BM;         // NN % 32 == 0, no bounds needed
    int tx = tid % CG;                  // col group -> cols tx*8 .. tx*8+7
    int ty = tid / CG;                  // row group -> rows ty*RPT .. +RPT-1

    float acc[RPT][8];
#pragma unroll
    for (int r = 0; r < RPT; ++r)
#pragma unroll
        for (int c = 0; c < 8; ++c) acc[r][c] = 0.f;

    int ar = tid / 8;                   // 0..31 row within tile (A staging)
    int ac = (tid % 8) * 4;             // 0..28 k-col within tile

    for (int k0 = 0; k0 < 128; k0 += BK) {
        // stage A (32x32, transposed)
        float4 av = *(const float4*)&H[(size_t)(row0 + ar) * 128 + k0 + ac];
        At[ac + 0][ar] = av.x;
        At[ac + 1][ar] = av.y;
        At[ac + 2][ar] = av.z;
        At[ac + 3][ar] = av.w;
        // stage W (32 x N2): combined [Wl | Wr]
        constexpr int NF4 = (BK * N2) / (256 * 4);   // 8 or 4 float4 per thread
#pragma unroll
        for (int p = 0; p < NF4; ++p) {
            int idx = (p * 256 + tid) * 4;           // float index into [BK][N2]
            int k = idx / N2;
            int j = idx % N2;
            float4 wv;
            if (j < NOUT) wv = *(const float4*)&Wl[(size_t)(k0 + k) * NOUT + j];
            else          wv = *(const float4*)&Wr[(size_t)(k0 + k) * NOUT + (j - NOUT)];
            *(float4*)&Wt[k][j] = wv;
        }
        __syncthreads();

#pragma unroll
        for (int kk = 0; kk < BK; ++kk) {
            float a[RPT];
#pragma unroll
            for (int r = 0; r < RPT; ++r) a[r] = At[kk][ty * RPT + r];
            float w[8];
#pragma unroll
            for (int c = 0; c < 8; ++c) w[c] = Wt[kk][tx * 8 + c];
#pragma unroll
            for (int r = 0; r < RPT; ++r)
#pragma unroll
                for (int c = 0; c < 8; ++c) acc[r][c] += a[r] * w[c];
        }
        __syncthreads();
    }

    // epilogue: cols tx*8..+7 lie entirely in Y-half or Z-half
    int j0 = tx * 8;
#pragma unroll
    for (int r = 0; r < RPT; ++r) {
        int row = row0 + ty * RPT + r;
        float* dstp = (j0 < NOUT) ? &Y[(size_t)row * NOUT + j0]
                                  : &Z[(size_t)row * NOUT + (j0 - NOUT)];
        float4 v0 = {acc[r][0], acc[r][1], acc[r][2], acc[r][3]};
        float4 v1 = {acc[r][4], acc[r][5], acc[r][6], acc[r][7]};
        *(float4*)&dstp[0] = v0;
        *(float4*)&dstp[4] = v1;
    }
}

// ---------------- aggregation:  out = mean_{nbr} Y[nbr] + Z[n] + b  (opt LeakyReLU) ----

template <int NOUT, bool RELU>
__global__ __launch_bounds__(256) void k_agg(const float* __restrict__ Y,
                                             const float* __restrict__ Z,
                                             const int* __restrict__ row_off,
                                             const int* __restrict__ csr,
                                             const float* __restrict__ b,
                                             float* __restrict__ out) {
    int wave = threadIdx.x >> 6;
    int lane = threadIdx.x & 63;
    int n = blockIdx.x * 4 + wave;
    if (n >= NN) return;
    int beg = row_off[n];
    int end = row_off[n + 1];
    float inv = (end > beg) ? 1.0f / (float)(end - beg) : 0.0f;

    if (NOUT == 128) {
        float2 acc = {0.f, 0.f};
        for (int e = beg; e < end; ++e) {
            int s = csr[e];
            float2 v = *(const float2*)&Y[(size_t)s * 128 + lane * 2];
            acc.x += v.x;
            acc.y += v.y;
        }
        float2 z = *(const float2*)&Z[(size_t)n * 128 + lane * 2];
        float2 bb = *(const float2*)&b[lane * 2];
        float ox = acc.x * inv + z.x + bb.x;
        float oy = acc.y * inv + z.y + bb.y;
        if (RELU) {
            ox = ox > 0.f ? ox : 0.1f * ox;
            oy = oy > 0.f ? oy : 0.1f * oy;
        }
        *(float2*)&out[(size_t)n * 128 + lane * 2] = make_float2(ox, oy);
    } else {
        float acc = 0.f;
        for (int e = beg; e < end; ++e) {
            int s = csr[e];
            acc += Y[(size_t)s * 64 + lane];
        }
        float o = acc * inv + Z[(size_t)n * 64 + lane] + b[lane];
        if (RELU) o = o > 0.f ? o : 0.1f * o;
        out[(size_t)n * 64 + lane] = o;
    }
}

// ---------------- launch ----------------

extern "C" void kernel_launch(void* const* d_in, const int* in_sizes, int n_in,
                              void* d_out, int out_size, void* d_ws, size_t ws_size,
                              hipStream_t stream) {
    const float* x        = (const float*)d_in[0];
    const int*   ei       = (const int*)d_in[1];
    const float* Wl_stack = (const float*)d_in[2];
    const float* Wr_stack = (const float*)d_in[3];
    const float* b_stack  = (const float*)d_in[4];
    const float* Wl_out   = (const float*)d_in[5];
    const float* Wr_out   = (const float*)d_in[6];
    const float* b_out    = (const float*)d_in[7];
    float* out = (float*)d_out;

    // workspace layout: float buffers first (16B alignment), ints after
    float* hbuf = (float*)d_ws;                       // [NN,128]
    float* Y    = hbuf + (size_t)NN * 128;            // [NN,128]
    float* Z    = Y + (size_t)NN * 128;               // [NN,128]
    int* deg     = (int*)(Z + (size_t)NN * 128);      // [NN]
    int* row_off = deg + NN;                          // [NN+1]
    int* cursor  = row_off + NN + 1;                  // [NN]
    int* csr     = cursor + NN;                       // [NE]
    int* local   = csr + NE;                          // [NN]
    int* bsum    = local + NN;                        // [512]
    int* bpre    = bsum + 512;                        // [512]

    const int* src = ei;
    const int* dst = ei + NE;

    // CSR build (per call; graph-capture safe)
    hipMemsetAsync(deg, 0, NN * sizeof(int), stream);
    k_hist<<<(NE + 255) / 256, 256, 0, stream>>>(dst, deg);
    k_scan1<<<SCAN_B, 256, 0, stream>>>(deg, local, bsum);
    k_scan2<<<1, 512, 0, stream>>>(bsum, bpre);
    k_scan3<<<SCAN_B, 256, 0, stream>>>(local, bpre, row_off, cursor);
    k_fill<<<(NE + 255) / 256, 256, 0, stream>>>(src, dst, cursor, csr);

    const float* hin = x;
    for (int l = 0; l < 3; ++l) {
        k_gemm<128><<<NN / 32, 256, 0, stream>>>(hin, Wl_stack + l * 16384,
                                                 Wr_stack + l * 16384, Y, Z);
        k_agg<128, true><<<NN / 4, 256, 0, stream>>>(Y, Z, row_off, csr,
                                                     b_stack + l * 128, hbuf);
        hin = hbuf;
    }
    k_gemm<64><<<NN / 32, 256, 0, stream>>>(hin, Wl_out, Wr_out, Y, Z);
    k_agg<64, false><<<NN / 4, 256, 0, stream>>>(Y, Z, row_off, csr, b_out, out);
}

// Round 5
// 961.536 us; speedup vs baseline: 1.4937x; 1.2608x over previous
//
#include <hip/hip_runtime.h>

#define NN 100000
#define NNP 100096            // padded row count (multiple of 128)
#define NE 1600000
#define SCAN_B ((NN + 255) / 256)   // 391

typedef __attribute__((ext_vector_type(8))) short bf16x8;
typedef __attribute__((ext_vector_type(4))) float f32x4;

__device__ __forceinline__ float bf2f(unsigned short u) {
    unsigned int v = ((unsigned int)u) << 16;
    return __builtin_bit_cast(float, v);
}
__device__ __forceinline__ unsigned short f2bf(float f) {
    unsigned int u = __builtin_bit_cast(unsigned int, f);
    u += 0x7FFFu + ((u >> 16) & 1u);          // RNE
    return (unsigned short)(u >> 16);
}

// ---------------- CSR build ----------------

__global__ __launch_bounds__(256) void k_hist(const int* __restrict__ dst,
                                              int* __restrict__ deg) {
    int e = blockIdx.x * 256 + threadIdx.x;
    if (e < NE) atomicAdd(&deg[dst[e]], 1);
}

__global__ __launch_bounds__(256) void k_scan1(const int* __restrict__ deg,
                                               int* __restrict__ local,
                                               int* __restrict__ bsum) {
    __shared__ int s[256];
    int tid = threadIdx.x;
    int i = blockIdx.x * 256 + tid;
    int v = (i < NN) ? deg[i] : 0;
    s[tid] = v;
    __syncthreads();
#pragma unroll
    for (int off = 1; off < 256; off <<= 1) {
        int t = (tid >= off) ? s[tid - off] : 0;
        __syncthreads();
        if (tid >= off) s[tid] += t;
        __syncthreads();
    }
    if (i < NN) local[i] = s[tid] - v;
    if (tid == 255) bsum[blockIdx.x] = s[255];
}

__global__ __launch_bounds__(512) void k_scan2(int* __restrict__ bsum,
                                               int* __restrict__ bpre) {
    __shared__ int s[512];
    int tid = threadIdx.x;
    int v = (tid < SCAN_B) ? bsum[tid] : 0;
    s[tid] = v;
    __syncthreads();
#pragma unroll
    for (int off = 1; off < 512; off <<= 1) {
        int t = (tid >= off) ? s[tid - off] : 0;
        __syncthreads();
        if (tid >= off) s[tid] += t;
        __syncthreads();
    }
    if (tid < SCAN_B) bpre[tid] = s[tid] - v;
}

__global__ __launch_bounds__(256) void k_scan3(const int* __restrict__ local,
                                               const int* __restrict__ bpre,
                                               int* __restrict__ row_off,
                                               int* __restrict__ cursor) {
    int i = blockIdx.x * 256 + threadIdx.x;
    if (i < NN) {
        int r = local[i] + bpre[blockIdx.x];
        row_off[i] = r;
        cursor[i] = r;
    }
    if (i == 0) row_off[NN] = NE;
}

__global__ __launch_bounds__(256) void k_fill(const int* __restrict__ src,
                                              const int* __restrict__ dst,
                                              int* __restrict__ cursor,
                                              int* __restrict__ csr) {
    int e = blockIdx.x * 256 + threadIdx.x;
    if (e < NE) {
        int p = atomicAdd(&cursor[dst[e]], 1);
        csr[p] = src[e];
    }
}

// ---------------- prep: x -> bf16, W -> WT bf16 ----------------

__global__ __launch_bounds__(256) void k_prep_x(const float* __restrict__ x,
                                                unsigned short* __restrict__ xb) {
    int i = blockIdx.x * 256 + threadIdx.x;    // group of 8 floats
    if (i >= NN * 16) return;
    const float4* p = (const float4*)x + (size_t)i * 2;
    float4 a = p[0], b = p[1];
    uint4 o;
    o.x = (unsigned int)f2bf(a.x) | ((unsigned int)f2bf(a.y) << 16);
    o.y = (unsigned int)f2bf(a.z) | ((unsigned int)f2bf(a.w) << 16);
    o.z = (unsigned int)f2bf(b.x) | ((unsigned int)f2bf(b.y) << 16);
    o.w = (unsigned int)f2bf(b.z) | ((unsigned int)f2bf(b.w) << 16);
    ((uint4*)xb)[i] = o;
}

// WT layout: layers 0..2: [256][128] each at l*32768; layer 3: [128][128] at 98304
__global__ __launch_bounds__(256) void k_prep_wt(const float* __restrict__ Wl_stack,
                                                 const float* __restrict__ Wr_stack,
                                                 const float* __restrict__ Wl_out,
                                                 const float* __restrict__ Wr_out,
                                                 unsigned short* __restrict__ WT) {
    int i = blockIdx.x * 256 + threadIdx.x;
    const int L3OFF = 3 * 256 * 128;     // 98304
    const int TOT = L3OFF + 128 * 128;   // 114688
    if (i >= TOT) return;
    float v;
    if (i < L3OFF) {
        int l = i / (256 * 128);
        int r = i % (256 * 128);
        int c = r / 128;                 // output col within [Wl|Wr]
        int k = r % 128;
        v = (c < 128) ? Wl_stack[(size_t)(l * 128 + k) * 128 + c]
                      : Wr_stack[(size_t)(l * 128 + k) * 128 + (c - 128)];
    } else {
        int r = i - L3OFF;
        int c = r / 128;
        int k = r % 128;
        v = (c < 64) ? Wl_out[(size_t)k * 64 + c]
                     : Wr_out[(size_t)k * 64 + (c - 64)];
    }
    WT[i] = f2bf(v);
}

// ---------------- MFMA dual GEMM: Y|Z = A @ [Wl|Wr]  (bf16 in, bf16 out) ----------------
// A: [NNP,128] bf16. WT: [N2][128] bf16 (pre-transposed). Y,Z: [NNP,NOUT] bf16.
// 256 thr = 4 waves; block covers 128 rows; wave 32 rows (2 strips of 16).
// mfma_f32_16x16x32_bf16: A row=l&15,k=(l>>4)*8+i ; B col=l&15,k=(l>>4)*8+i ;
// D col=l&15, row=(l>>4)*4+reg (verified layout, learn_hip m89/m91).

template <int NOUT>
__global__ __launch_bounds__(256) void k_mm(const unsigned short* __restrict__ A,
                                            const unsigned short* __restrict__ WT,
                                            unsigned short* __restrict__ Y,
                                            unsigned short* __restrict__ Z) {
    constexpr int N2 = 2 * NOUT;
    constexpr int CGS = N2 / 16;        // 16 or 8 col-groups
    constexpr int HALVES = CGS / 8;     // 2 or 1
    int tid = threadIdx.x;
    int wave = tid >> 6, l = tid & 63;
    int lrow = l & 15, lk8 = (l >> 4) * 8;
    int rbase = blockIdx.x * 128 + wave * 32;

#pragma unroll
    for (int h = 0; h < HALVES; ++h) {
        bf16x8 bf[8][4];
#pragma unroll
        for (int cg8 = 0; cg8 < 8; ++cg8) {
            int c = (h * 8 + cg8) * 16 + lrow;
#pragma unroll
            for (int ks = 0; ks < 4; ++ks)
                bf[cg8][ks] = *(const bf16x8*)(WT + (size_t)c * 128 + ks * 32 + lk8);
        }
#pragma unroll
        for (int s = 0; s < 2; ++s) {
            int row = rbase + s * 16 + lrow;
            bf16x8 af[4];
#pragma unroll
            for (int ks = 0; ks < 4; ++ks)
                af[ks] = *(const bf16x8*)(A + (size_t)row * 128 + ks * 32 + lk8);
#pragma unroll
            for (int cg8 = 0; cg8 < 8; ++cg8) {
                f32x4 acc = {0.f, 0.f, 0.f, 0.f};
#pragma unroll
                for (int ks = 0; ks < 4; ++ks)
                    acc = __builtin_amdgcn_mfma_f32_16x16x32_bf16(af[ks], bf[cg8][ks], acc, 0, 0, 0);
                int ccol = (h * 8 + cg8) * 16 + lrow;
                unsigned short* dstp = (ccol < NOUT) ? Y : Z;
                int col = (ccol < NOUT) ? ccol : ccol - NOUT;
                int r0 = rbase + s * 16 + (l >> 4) * 4;
#pragma unroll
                for (int r = 0; r < 4; ++r)
                    dstp[(size_t)(r0 + r) * NOUT + col] = f2bf(acc[r]);
            }
        }
    }
}

// ---------------- aggregation (bf16 gather, fp32 accum) ----------------

template <int NOUT, bool RELU>
__global__ __launch_bounds__(256) void k_aggb(const unsigned short* __restrict__ Y,
                                              const unsigned short* __restrict__ Z,
                                              const int* __restrict__ row_off,
                                              const int* __restrict__ csr,
                                              const float* __restrict__ b,
                                              unsigned short* __restrict__ outb,
                                              float* __restrict__ outf) {
    int wave = threadIdx.x >> 6;
    int lane = threadIdx.x & 63;
    int n = blockIdx.x * 4 + wave;
    if (n >= NN) return;
    int beg = row_off[n], end = row_off[n + 1];
    float inv = (end > beg) ? 1.0f / (float)(end - beg) : 0.0f;

    if (NOUT == 128) {
        float a0 = 0.f, a1 = 0.f;
        for (int e = beg; e < end; ++e) {
            int s = csr[e];
            unsigned int v = *(const unsigned int*)(Y + (size_t)s * 128 + lane * 2);
            a0 += __builtin_bit_cast(float, v << 16);
            a1 += __builtin_bit_cast(float, v & 0xFFFF0000u);
        }
        unsigned int zv = *(const unsigned int*)(Z + (size_t)n * 128 + lane * 2);
        float z0 = __builtin_bit_cast(float, zv << 16);
        float z1 = __builtin_bit_cast(float, zv & 0xFFFF0000u);
        float2 bb = *(const float2*)(b + lane * 2);
        float o0 = a0 * inv + z0 + bb.x;
        float o1 = a1 * inv + z1 + bb.y;
        if (RELU) {
            o0 = o0 > 0.f ? o0 : 0.1f * o0;
            o1 = o1 > 0.f ? o1 : 0.1f * o1;
        }
        unsigned int w = (unsigned int)f2bf(o0) | ((unsigned int)f2bf(o1) << 16);
        *(unsigned int*)(outb + (size_t)n * 128 + lane * 2) = w;
    } else {
        float a0 = 0.f;
        for (int e = beg; e < end; ++e) {
            int s = csr[e];
            a0 += bf2f(Y[(size_t)s * 64 + lane]);
        }
        float o = a0 * inv + bf2f(Z[(size_t)n * 64 + lane]) + b[lane];
        if (RELU) o = o > 0.f ? o : 0.1f * o;
        outf[(size_t)n * 64 + lane] = o;
    }
}

// ---------------- launch ----------------

extern "C" void kernel_launch(void* const* d_in, const int* in_sizes, int n_in,
                              void* d_out, int out_size, void* d_ws, size_t ws_size,
                              hipStream_t stream) {
    const float* x        = (const float*)d_in[0];
    const int*   ei       = (const int*)d_in[1];
    const float* Wl_stack = (const float*)d_in[2];
    const float* Wr_stack = (const float*)d_in[3];
    const float* b_stack  = (const float*)d_in[4];
    const float* Wl_out   = (const float*)d_in[5];
    const float* Wr_out   = (const float*)d_in[6];
    const float* b_out    = (const float*)d_in[7];
    float* out = (float*)d_out;

    unsigned short* xb = (unsigned short*)d_ws;        // [NNP,128]
    unsigned short* hb = xb + (size_t)NNP * 128;       // [NNP,128]
    unsigned short* Yb = hb + (size_t)NNP * 128;       // [NNP,128]
    unsigned short* Zb = Yb + (size_t)NNP * 128;       // [NNP,128]
    unsigned short* WT = Zb + (size_t)NNP * 128;       // 114688
    int* deg     = (int*)(WT + 114688);
    int* row_off = deg + NN;
    int* cursor  = row_off + NN + 1;
    int* csr     = cursor + NN;
    int* local   = csr + NE;
    int* bsum    = local + NN;
    int* bpre    = bsum + 512;

    const int* src = ei;
    const int* dst = ei + NE;

    // CSR build
    hipMemsetAsync(deg, 0, NN * sizeof(int), stream);
    k_hist<<<(NE + 255) / 256, 256, 0, stream>>>(dst, deg);
    k_scan1<<<SCAN_B, 256, 0, stream>>>(deg, local, bsum);
    k_scan2<<<1, 512, 0, stream>>>(bsum, bpre);
    k_scan3<<<SCAN_B, 256, 0, stream>>>(local, bpre, row_off, cursor);
    k_fill<<<(NE + 255) / 256, 256, 0, stream>>>(src, dst, cursor, csr);

    // prep
    k_prep_x<<<(NN * 16 + 255) / 256, 256, 0, stream>>>(x, xb);
    k_prep_wt<<<448, 256, 0, stream>>>(Wl_stack, Wr_stack, Wl_out, Wr_out, WT);

    // layers
    const unsigned short* hin = xb;
    for (int l = 0; l < 3; ++l) {
        k_mm<128><<<NNP / 128, 256, 0, stream>>>(hin, WT + l * 32768, Yb, Zb);
        k_aggb<128, true><<<(NN + 3) / 4, 256, 0, stream>>>(Yb, Zb, row_off, csr,
                                                            b_stack + l * 128, hb, nullptr);
        hin = hb;
    }
    k_mm<64><<<NNP / 128, 256, 0, stream>>>(hin, WT + 98304, Yb, Zb);
    k_aggb<64, false><<<(NN + 3) / 4, 256, 0, stream>>>(Yb, Zb, row_off, csr,
                                                        b_out, nullptr, out);
}

// Round 6
// 621.210 us; speedup vs baseline: 2.3121x; 1.5478x over previous
//
#include <hip/hip_runtime.h>

#define NN 100000
#define NNP 100096            // padded row count (multiple of 128)
#define NE 1600000
#define SCAN_B ((NN + 255) / 256)   // 391

typedef __attribute__((ext_vector_type(8))) short bf16x8;
typedef __attribute__((ext_vector_type(4))) float f32x4;

__device__ __forceinline__ float bf2f(unsigned short u) {
    unsigned int v = ((unsigned int)u) << 16;
    return __builtin_bit_cast(float, v);
}
__device__ __forceinline__ unsigned short f2bf(float f) {
    unsigned int u = __builtin_bit_cast(unsigned int, f);
    u += 0x7FFFu + ((u >> 16) & 1u);          // RNE
    return (unsigned short)(u >> 16);
}
__device__ __forceinline__ float bflo(unsigned int v) {
    return __builtin_bit_cast(float, v << 16);
}
__device__ __forceinline__ float bfhi(unsigned int v) {
    return __builtin_bit_cast(float, v & 0xFFFF0000u);
}

// ---------------- CSR build ----------------

__global__ __launch_bounds__(256) void k_hist(const int* __restrict__ dst,
                                              int* __restrict__ deg) {
    int e = blockIdx.x * 256 + threadIdx.x;
    if (e < NE) atomicAdd(&deg[dst[e]], 1);
}

__global__ __launch_bounds__(256) void k_scan1(const int* __restrict__ deg,
                                               int* __restrict__ local,
                                               int* __restrict__ bsum) {
    __shared__ int s[256];
    int tid = threadIdx.x;
    int i = blockIdx.x * 256 + tid;
    int v = (i < NN) ? deg[i] : 0;
    s[tid] = v;
    __syncthreads();
#pragma unroll
    for (int off = 1; off < 256; off <<= 1) {
        int t = (tid >= off) ? s[tid - off] : 0;
        __syncthreads();
        if (tid >= off) s[tid] += t;
        __syncthreads();
    }
    if (i < NN) local[i] = s[tid] - v;
    if (tid == 255) bsum[blockIdx.x] = s[255];
}

__global__ __launch_bounds__(512) void k_scan2(int* __restrict__ bsum,
                                               int* __restrict__ bpre) {
    __shared__ int s[512];
    int tid = threadIdx.x;
    int v = (tid < SCAN_B) ? bsum[tid] : 0;
    s[tid] = v;
    __syncthreads();
#pragma unroll
    for (int off = 1; off < 512; off <<= 1) {
        int t = (tid >= off) ? s[tid - off] : 0;
        __syncthreads();
        if (tid >= off) s[tid] += t;
        __syncthreads();
    }
    if (tid < SCAN_B) bpre[tid] = s[tid] - v;
}

__global__ __launch_bounds__(256) void k_scan3(const int* __restrict__ local,
                                               const int* __restrict__ bpre,
                                               int* __restrict__ row_off,
                                               int* __restrict__ cursor) {
    int i = blockIdx.x * 256 + threadIdx.x;
    if (i < NN) {
        int r = local[i] + bpre[blockIdx.x];
        row_off[i] = r;
        cursor[i] = r;
    }
    if (i == 0) row_off[NN] = NE;
}

__global__ __launch_bounds__(256) void k_fill(const int* __restrict__ src,
                                              const int* __restrict__ dst,
                                              int* __restrict__ cursor,
                                              int* __restrict__ csr) {
    int e = blockIdx.x * 256 + threadIdx.x;
    if (e < NE) {
        int p = atomicAdd(&cursor[dst[e]], 1);
        csr[p] = src[e];
    }
}

// ---------------- prep: x -> bf16, W -> WT bf16 ----------------

__global__ __launch_bounds__(256) void k_prep_x(const float* __restrict__ x,
                                                unsigned short* __restrict__ xb) {
    int i = blockIdx.x * 256 + threadIdx.x;    // group of 8 floats
    if (i >= NN * 16) return;
    const float4* p = (const float4*)x + (size_t)i * 2;
    float4 a = p[0], b = p[1];
    uint4 o;
    o.x = (unsigned int)f2bf(a.x) | ((unsigned int)f2bf(a.y) << 16);
    o.y = (unsigned int)f2bf(a.z) | ((unsigned int)f2bf(a.w) << 16);
    o.z = (unsigned int)f2bf(b.x) | ((unsigned int)f2bf(b.y) << 16);
    o.w = (unsigned int)f2bf(b.z) | ((unsigned int)f2bf(b.w) << 16);
    ((uint4*)xb)[i] = o;
}

// WT layout: layers 0..2: [256][128] each at l*32768; layer 3: [128][128] at 98304
__global__ __launch_bounds__(256) void k_prep_wt(const float* __restrict__ Wl_stack,
                                                 const float* __restrict__ Wr_stack,
                                                 const float* __restrict__ Wl_out,
                                                 const float* __restrict__ Wr_out,
                                                 unsigned short* __restrict__ WT) {
    int i = blockIdx.x * 256 + threadIdx.x;
    const int L3OFF = 3 * 256 * 128;     // 98304
    const int TOT = L3OFF + 128 * 128;   // 114688
    if (i >= TOT) return;
    float v;
    if (i < L3OFF) {
        int l = i / (256 * 128);
        int r = i % (256 * 128);
        int c = r / 128;                 // output col within [Wl|Wr]
        int k = r % 128;
        v = (c < 128) ? Wl_stack[(size_t)(l * 128 + k) * 128 + c]
                      : Wr_stack[(size_t)(l * 128 + k) * 128 + (c - 128)];
    } else {
        int r = i - L3OFF;
        int c = r / 128;
        int k = r % 128;
        v = (c < 64) ? Wl_out[(size_t)k * 64 + c]
                     : Wr_out[(size_t)k * 64 + (c - 64)];
    }
    WT[i] = f2bf(v);
}

// ---------------- MFMA dual GEMM: Y|Z = A @ [Wl|Wr]  (bf16 in, bf16 out) ----------------

template <int NOUT>
__global__ __launch_bounds__(256) void k_mm(const unsigned short* __restrict__ A,
                                            const unsigned short* __restrict__ WT,
                                            unsigned short* __restrict__ Y,
                                            unsigned short* __restrict__ Z) {
    constexpr int N2 = 2 * NOUT;
    constexpr int CGS = N2 / 16;        // 16 or 8 col-groups
    constexpr int HALVES = CGS / 8;     // 2 or 1
    int tid = threadIdx.x;
    int wave = tid >> 6, l = tid & 63;
    int lrow = l & 15, lk8 = (l >> 4) * 8;
    int rbase = blockIdx.x * 128 + wave * 32;

#pragma unroll
    for (int h = 0; h < HALVES; ++h) {
        bf16x8 bf[8][4];
#pragma unroll
        for (int cg8 = 0; cg8 < 8; ++cg8) {
            int c = (h * 8 + cg8) * 16 + lrow;
#pragma unroll
            for (int ks = 0; ks < 4; ++ks)
                bf[cg8][ks] = *(const bf16x8*)(WT + (size_t)c * 128 + ks * 32 + lk8);
        }
#pragma unroll
        for (int s = 0; s < 2; ++s) {
            int row = rbase + s * 16 + lrow;
            bf16x8 af[4];
#pragma unroll
            for (int ks = 0; ks < 4; ++ks)
                af[ks] = *(const bf16x8*)(A + (size_t)row * 128 + ks * 32 + lk8);
#pragma unroll
            for (int cg8 = 0; cg8 < 8; ++cg8) {
                f32x4 acc = {0.f, 0.f, 0.f, 0.f};
#pragma unroll
                for (int ks = 0; ks < 4; ++ks)
                    acc = __builtin_amdgcn_mfma_f32_16x16x32_bf16(af[ks], bf[cg8][ks], acc, 0, 0, 0);
                int ccol = (h * 8 + cg8) * 16 + lrow;
                unsigned short* dstp = (ccol < NOUT) ? Y : Z;
                int col = (ccol < NOUT) ? ccol : ccol - NOUT;
                int r0 = rbase + s * 16 + (l >> 4) * 4;
#pragma unroll
                for (int r = 0; r < 4; ++r)
                    dstp[(size_t)(r0 + r) * NOUT + col] = f2bf(acc[r]);
            }
        }
    }
}

// ---------------- aggregation (bf16 gather, fp32 accum, 8x/4x unrolled for MLP) ----

template <int NOUT, bool RELU>
__global__ __launch_bounds__(256) void k_aggb(const unsigned short* __restrict__ Y,
                                              const unsigned short* __restrict__ Z,
                                              const int* __restrict__ row_off,
                                              const int* __restrict__ csr,
                                              const float* __restrict__ b,
                                              unsigned short* __restrict__ outb,
                                              float* __restrict__ outf) {
    int wave = threadIdx.x >> 6;
    int lane = threadIdx.x & 63;
    int n = blockIdx.x * 4 + wave;
    if (n >= NN) return;
    int beg = row_off[n], end = row_off[n + 1];
    float inv = (end > beg) ? 1.0f / (float)(end - beg) : 0.0f;

    if (NOUT == 128) {
        const int lane2 = lane * 2;
        float a0 = 0.f, a1 = 0.f;
        int e = beg;
        // 8-deep MLP main loop
        for (; e + 8 <= end; e += 8) {
            int s0 = csr[e + 0], s1 = csr[e + 1], s2 = csr[e + 2], s3 = csr[e + 3];
            int s4 = csr[e + 4], s5 = csr[e + 5], s6 = csr[e + 6], s7 = csr[e + 7];
            unsigned int v0 = *(const unsigned int*)(Y + (size_t)s0 * 128 + lane2);
            unsigned int v1 = *(const unsigned int*)(Y + (size_t)s1 * 128 + lane2);
            unsigned int v2 = *(const unsigned int*)(Y + (size_t)s2 * 128 + lane2);
            unsigned int v3 = *(const unsigned int*)(Y + (size_t)s3 * 128 + lane2);
            unsigned int v4 = *(const unsigned int*)(Y + (size_t)s4 * 128 + lane2);
            unsigned int v5 = *(const unsigned int*)(Y + (size_t)s5 * 128 + lane2);
            unsigned int v6 = *(const unsigned int*)(Y + (size_t)s6 * 128 + lane2);
            unsigned int v7 = *(const unsigned int*)(Y + (size_t)s7 * 128 + lane2);
            a0 += bflo(v0) + bflo(v1) + bflo(v2) + bflo(v3)
                + bflo(v4) + bflo(v5) + bflo(v6) + bflo(v7);
            a1 += bfhi(v0) + bfhi(v1) + bfhi(v2) + bfhi(v3)
                + bfhi(v4) + bfhi(v5) + bfhi(v6) + bfhi(v7);
        }
        // 4-deep
        for (; e + 4 <= end; e += 4) {
            int s0 = csr[e + 0], s1 = csr[e + 1], s2 = csr[e + 2], s3 = csr[e + 3];
            unsigned int v0 = *(const unsigned int*)(Y + (size_t)s0 * 128 + lane2);
            unsigned int v1 = *(const unsigned int*)(Y + (size_t)s1 * 128 + lane2);
            unsigned int v2 = *(const unsigned int*)(Y + (size_t)s2 * 128 + lane2);
            unsigned int v3 = *(const unsigned int*)(Y + (size_t)s3 * 128 + lane2);
            a0 += bflo(v0) + bflo(v1) + bflo(v2) + bflo(v3);
            a1 += bfhi(v0) + bfhi(v1) + bfhi(v2) + bfhi(v3);
        }
        // tail
        for (; e < end; ++e) {
            int s = csr[e];
            unsigned int v = *(const unsigned int*)(Y + (size_t)s * 128 + lane2);
            a0 += bflo(v);
            a1 += bfhi(v);
        }
        unsigned int zv = *(const unsigned int*)(Z + (size_t)n * 128 + lane2);
        float2 bb = *(const float2*)(b + lane2);
        float o0 = a0 * inv + bflo(zv) + bb.x;
        float o1 = a1 * inv + bfhi(zv) + bb.y;
        if (RELU) {
            o0 = o0 > 0.f ? o0 : 0.1f * o0;
            o1 = o1 > 0.f ? o1 : 0.1f * o1;
        }
        unsigned int w = (unsigned int)f2bf(o0) | ((unsigned int)f2bf(o1) << 16);
        *(unsigned int*)(outb + (size_t)n * 128 + lane2) = w;
    } else {
        float a0 = 0.f;
        int e = beg;
        for (; e + 8 <= end; e += 8) {
            int s0 = csr[e + 0], s1 = csr[e + 1], s2 = csr[e + 2], s3 = csr[e + 3];
            int s4 = csr[e + 4], s5 = csr[e + 5], s6 = csr[e + 6], s7 = csr[e + 7];
            float f0 = bf2f(Y[(size_t)s0 * 64 + lane]);
            float f1 = bf2f(Y[(size_t)s1 * 64 + lane]);
            float f2 = bf2f(Y[(size_t)s2 * 64 + lane]);
            float f3 = bf2f(Y[(size_t)s3 * 64 + lane]);
            float f4 = bf2f(Y[(size_t)s4 * 64 + lane]);
            float f5 = bf2f(Y[(size_t)s5 * 64 + lane]);
            float f6 = bf2f(Y[(size_t)s6 * 64 + lane]);
            float f7 = bf2f(Y[(size_t)s7 * 64 + lane]);
            a0 += f0 + f1 + f2 + f3 + f4 + f5 + f6 + f7;
        }
        for (; e + 4 <= end; e += 4) {
            int s0 = csr[e + 0], s1 = csr[e + 1], s2 = csr[e + 2], s3 = csr[e + 3];
            float f0 = bf2f(Y[(size_t)s0 * 64 + lane]);
            float f1 = bf2f(Y[(size_t)s1 * 64 + lane]);
            float f2 = bf2f(Y[(size_t)s2 * 64 + lane]);
            float f3 = bf2f(Y[(size_t)s3 * 64 + lane]);
            a0 += f0 + f1 + f2 + f3;
        }
        for (; e < end; ++e) {
            int s = csr[e];
            a0 += bf2f(Y[(size_t)s * 64 + lane]);
        }
        float o = a0 * inv + bf2f(Z[(size_t)n * 64 + lane]) + b[lane];
        if (RELU) o = o > 0.f ? o : 0.1f * o;
        outf[(size_t)n * 64 + lane] = o;
    }
}

// ---------------- launch ----------------

extern "C" void kernel_launch(void* const* d_in, const int* in_sizes, int n_in,
                              void* d_out, int out_size, void* d_ws, size_t ws_size,
                              hipStream_t stream) {
    const float* x        = (const float*)d_in[0];
    const int*   ei       = (const int*)d_in[1];
    const float* Wl_stack = (const float*)d_in[2];
    const float* Wr_stack = (const float*)d_in[3];
    const float* b_stack  = (const float*)d_in[4];
    const float* Wl_out   = (const float*)d_in[5];
    const float* Wr_out   = (const float*)d_in[6];
    const float* b_out    = (const float*)d_in[7];
    float* out = (float*)d_out;

    unsigned short* xb = (unsigned short*)d_ws;        // [NNP,128]
    unsigned short* hb = xb + (size_t)NNP * 128;       // [NNP,128]
    unsigned short* Yb = hb + (size_t)NNP * 128;       // [NNP,128]
    unsigned short* Zb = Yb + (size_t)NNP * 128;       // [NNP,128]
    unsigned short* WT = Zb + (size_t)NNP * 128;       // 114688
    int* deg     = (int*)(WT + 114688);
    int* row_off = deg + NN;
    int* cursor  = row_off + NN + 1;
    int* csr     = cursor + NN;
    int* local   = csr + NE;
    int* bsum    = local + NN;
    int* bpre    = bsum + 512;

    const int* src = ei;
    const int* dst = ei + NE;

    // CSR build
    hipMemsetAsync(deg, 0, NN * sizeof(int), stream);
    k_hist<<<(NE + 255) / 256, 256, 0, stream>>>(dst, deg);
    k_scan1<<<SCAN_B, 256, 0, stream>>>(deg, local, bsum);
    k_scan2<<<1, 512, 0, stream>>>(bsum, bpre);
    k_scan3<<<SCAN_B, 256, 0, stream>>>(local, bpre, row_off, cursor);
    k_fill<<<(NE + 255) / 256, 256, 0, stream>>>(src, dst, cursor, csr);

    // prep
    k_prep_x<<<(NN * 16 + 255) / 256, 256, 0, stream>>>(x, xb);
    k_prep_wt<<<448, 256, 0, stream>>>(Wl_stack, Wr_stack, Wl_out, Wr_out, WT);

    // layers
    const unsigned short* hin = xb;
    for (int l = 0; l < 3; ++l) {
        k_mm<128><<<NNP / 128, 256, 0, stream>>>(hin, WT + l * 32768, Yb, Zb);
        k_aggb<128, true><<<(NN + 3) / 4, 256, 0, stream>>>(Yb, Zb, row_off, csr,
                                                            b_stack + l * 128, hb, nullptr);
        hin = hb;
    }
    k_mm<64><<<NNP / 128, 256, 0, stream>>>(hin, WT + 98304, Yb, Zb);
    k_aggb<64, false><<<(NN + 3) / 4, 256, 0, stream>>>(Yb, Zb, row_off, csr,
                                                        b_out, nullptr, out);
}

// Round 7
// 484.298 us; speedup vs baseline: 2.9657x; 1.2827x over previous
//
#include <hip/hip_runtime.h>

#define NN 100000
#define NNP 100096            // padded row count (multiple of 128)
#define NE 1600000
#define NBK 391               // node buckets of 256 (dst >> 8)
#define SCCH 4096             // edges per scatter/hist block
#define NSC ((NE + SCCH - 1) / SCCH)   // 391

typedef __attribute__((ext_vector_type(8))) short bf16x8;
typedef __attribute__((ext_vector_type(4))) float f32x4;

__device__ __forceinline__ float bf2f(unsigned short u) {
    unsigned int v = ((unsigned int)u) << 16;
    return __builtin_bit_cast(float, v);
}
__device__ __forceinline__ unsigned short f2bf(float f) {
    unsigned int u = __builtin_bit_cast(unsigned int, f);
    u += 0x7FFFu + ((u >> 16) & 1u);          // RNE
    return (unsigned short)(u >> 16);
}
__device__ __forceinline__ float bflo(unsigned int v) {
    return __builtin_bit_cast(float, v << 16);
}
__device__ __forceinline__ float bfhi(unsigned int v) {
    return __builtin_bit_cast(float, v & 0xFFFF0000u);
}

// ---------------- bucketed CSR build ----------------
// bucket = dst >> 8 (256 nodes per bucket, NBK buckets)

__global__ __launch_bounds__(256) void kb_hist(const int* __restrict__ dst,
                                               int* __restrict__ bcnt) {
    __shared__ int lh[NBK];
    int tid = threadIdx.x;
    for (int i = tid; i < NBK; i += 256) lh[i] = 0;
    __syncthreads();
    int base = blockIdx.x * SCCH;
    int lim = min(SCCH, NE - base);
    for (int i = tid; i < lim; i += 256)
        atomicAdd(&lh[dst[base + i] >> 8], 1);
    __syncthreads();
    for (int i = tid; i < NBK; i += 256)
        if (lh[i]) atomicAdd(&bcnt[i], lh[i]);
}

__global__ __launch_bounds__(512) void kb_scan(const int* __restrict__ bcnt,
                                               int* __restrict__ boff,
                                               int* __restrict__ bcur) {
    __shared__ int s[512];
    int tid = threadIdx.x;
    int v = (tid < NBK) ? bcnt[tid] : 0;
    s[tid] = v;
    __syncthreads();
#pragma unroll
    for (int off = 1; off < 512; off <<= 1) {
        int t = (tid >= off) ? s[tid - off] : 0;
        __syncthreads();
        if (tid >= off) s[tid] += t;
        __syncthreads();
    }
    if (tid < NBK) {
        int e = s[tid] - v;       // exclusive
        boff[tid] = e;
        bcur[tid] = e;
    }
    if (tid == 0) boff[NBK] = NE;
}

__global__ __launch_bounds__(256) void kb_scatter(const int* __restrict__ src,
                                                  const int* __restrict__ dst,
                                                  int* __restrict__ bcur,
                                                  unsigned long long* __restrict__ ebuf) {
    __shared__ int lh[NBK], lbase[NBK];
    int tid = threadIdx.x;
    for (int i = tid; i < NBK; i += 256) lh[i] = 0;
    __syncthreads();
    int base = blockIdx.x * SCCH;
    int lim = min(SCCH, NE - base);
    // pass 1: local bucket hist
    for (int i = tid; i < lim; i += 256)
        atomicAdd(&lh[dst[base + i] >> 8], 1);
    __syncthreads();
    // reserve global ranges (one atomic per block-bucket)
    for (int i = tid; i < NBK; i += 256)
        lbase[i] = lh[i] ? atomicAdd(&bcur[i], lh[i]) : 0;
    __syncthreads();
    for (int i = tid; i < NBK; i += 256) lh[i] = 0;
    __syncthreads();
    // pass 2: place edges
    for (int i = tid; i < lim; i += 256) {
        int d = dst[base + i];
        int s = src[base + i];
        int b = d >> 8;
        int off = atomicAdd(&lh[b], 1);
        ebuf[(size_t)lbase[b] + off] =
            ((unsigned long long)(unsigned)d << 32) | (unsigned)s;
    }
}

// one block per bucket: local CSR via LDS hist+scan+cursor
__global__ __launch_bounds__(256) void kb_csr(const unsigned long long* __restrict__ ebuf,
                                              const int* __restrict__ boff,
                                              int* __restrict__ row_off,
                                              int* __restrict__ csr) {
    __shared__ int sdeg[256], spre[256];
    int bkt = blockIdx.x;
    int tid = threadIdx.x;
    int nbase = bkt << 8;
    int ebeg = boff[bkt], eend = boff[bkt + 1];
    sdeg[tid] = 0;
    __syncthreads();
    for (int e = ebeg + tid; e < eend; e += 256) {
        int d = (int)(ebuf[e] >> 32);
        atomicAdd(&sdeg[d & 255], 1);
    }
    __syncthreads();
    spre[tid] = sdeg[tid];
    __syncthreads();
#pragma unroll
    for (int off = 1; off < 256; off <<= 1) {
        int t = (tid >= off) ? spre[tid - off] : 0;
        __syncthreads();
        if (tid >= off) spre[tid] += t;
        __syncthreads();
    }
    int excl = spre[tid] - sdeg[tid];
    if (nbase + tid < NN) row_off[nbase + tid] = ebeg + excl;
    if (bkt == 0 && tid == 0) row_off[NN] = NE;
    __syncthreads();
    sdeg[tid] = excl;                 // reuse as cursor
    __syncthreads();
    for (int e = ebeg + tid; e < eend; e += 256) {
        unsigned long long pv = ebuf[e];
        int d = (int)(pv >> 32);
        int s = (int)(unsigned)pv;
        int p = atomicAdd(&sdeg[d & 255], 1);
        csr[ebeg + p] = s;
    }
}

// ---------------- prep: x -> bf16, W -> WT bf16 ----------------

__global__ __launch_bounds__(256) void k_prep_x(const float* __restrict__ x,
                                                unsigned short* __restrict__ xb) {
    int i = blockIdx.x * 256 + threadIdx.x;    // group of 8 floats
    if (i >= NN * 16) return;
    const float4* p = (const float4*)x + (size_t)i * 2;
    float4 a = p[0], b = p[1];
    uint4 o;
    o.x = (unsigned int)f2bf(a.x) | ((unsigned int)f2bf(a.y) << 16);
    o.y = (unsigned int)f2bf(a.z) | ((unsigned int)f2bf(a.w) << 16);
    o.z = (unsigned int)f2bf(b.x) | ((unsigned int)f2bf(b.y) << 16);
    o.w = (unsigned int)f2bf(b.z) | ((unsigned int)f2bf(b.w) << 16);
    ((uint4*)xb)[i] = o;
}

// WT layout: layers 0..2: [256][128] each at l*32768; layer 3: [128][128] at 98304
__global__ __launch_bounds__(256) void k_prep_wt(const float* __restrict__ Wl_stack,
                                                 const float* __restrict__ Wr_stack,
                                                 const float* __restrict__ Wl_out,
                                                 const float* __restrict__ Wr_out,
                                                 unsigned short* __restrict__ WT) {
    int i = blockIdx.x * 256 + threadIdx.x;
    const int L3OFF = 3 * 256 * 128;     // 98304
    const int TOT = L3OFF + 128 * 128;   // 114688
    if (i >= TOT) return;
    float v;
    if (i < L3OFF) {
        int l = i / (256 * 128);
        int r = i % (256 * 128);
        int c = r / 128;                 // output col within [Wl|Wr]
        int k = r % 128;
        v = (c < 128) ? Wl_stack[(size_t)(l * 128 + k) * 128 + c]
                      : Wr_stack[(size_t)(l * 128 + k) * 128 + (c - 128)];
    } else {
        int r = i - L3OFF;
        int c = r / 128;
        int k = r % 128;
        v = (c < 64) ? Wl_out[(size_t)k * 64 + c]
                     : Wr_out[(size_t)k * 64 + (c - 64)];
    }
    WT[i] = f2bf(v);
}

// ---------------- MFMA dual GEMM: Y|Z = A @ [Wl|Wr]  (bf16 in, bf16 out) ----------------

template <int NOUT>
__global__ __launch_bounds__(256) void k_mm(const unsigned short* __restrict__ A,
                                            const unsigned short* __restrict__ WT,
                                            unsigned short* __restrict__ Y,
                                            unsigned short* __restrict__ Z) {
    constexpr int N2 = 2 * NOUT;
    constexpr int CGS = N2 / 16;        // 16 or 8 col-groups
    constexpr int HALVES = CGS / 8;     // 2 or 1
    int tid = threadIdx.x;
    int wave = tid >> 6, l = tid & 63;
    int lrow = l & 15, lk8 = (l >> 4) * 8;
    int rbase = blockIdx.x * 128 + wave * 32;

#pragma unroll
    for (int h = 0; h < HALVES; ++h) {
        bf16x8 bf[8][4];
#pragma unroll
        for (int cg8 = 0; cg8 < 8; ++cg8) {
            int c = (h * 8 + cg8) * 16 + lrow;
#pragma unroll
            for (int ks = 0; ks < 4; ++ks)
                bf[cg8][ks] = *(const bf16x8*)(WT + (size_t)c * 128 + ks * 32 + lk8);
        }
#pragma unroll
        for (int s = 0; s < 2; ++s) {
            int row = rbase + s * 16 + lrow;
            bf16x8 af[4];
#pragma unroll
            for (int ks = 0; ks < 4; ++ks)
                af[ks] = *(const bf16x8*)(A + (size_t)row * 128 + ks * 32 + lk8);
#pragma unroll
            for (int cg8 = 0; cg8 < 8; ++cg8) {
                f32x4 acc = {0.f, 0.f, 0.f, 0.f};
#pragma unroll
                for (int ks = 0; ks < 4; ++ks)
                    acc = __builtin_amdgcn_mfma_f32_16x16x32_bf16(af[ks], bf[cg8][ks], acc, 0, 0, 0);
                int ccol = (h * 8 + cg8) * 16 + lrow;
                unsigned short* dstp = (ccol < NOUT) ? Y : Z;
                int col = (ccol < NOUT) ? ccol : ccol - NOUT;
                int r0 = rbase + s * 16 + (l >> 4) * 4;
#pragma unroll
                for (int r = 0; r < 4; ++r)
                    dstp[(size_t)(r0 + r) * NOUT + col] = f2bf(acc[r]);
            }
        }
    }
}

// ---------------- aggregation (bf16 gather, fp32 accum, 8x/4x unrolled MLP) ----

template <int NOUT, bool RELU>
__global__ __launch_bounds__(256) void k_aggb(const unsigned short* __restrict__ Y,
                                              const unsigned short* __restrict__ Z,
                                              const int* __restrict__ row_off,
                                              const int* __restrict__ csr,
                                              const float* __restrict__ b,
                                              unsigned short* __restrict__ outb,
                                              float* __restrict__ outf) {
    int wave = threadIdx.x >> 6;
    int lane = threadIdx.x & 63;
    int n = blockIdx.x * 4 + wave;
    if (n >= NN) return;
    int beg = row_off[n], end = row_off[n + 1];
    float inv = (end > beg) ? 1.0f / (float)(end - beg) : 0.0f;

    if (NOUT == 128) {
        const int lane2 = lane * 2;
        float a0 = 0.f, a1 = 0.f;
        int e = beg;
        for (; e + 8 <= end; e += 8) {
            int s0 = csr[e + 0], s1 = csr[e + 1], s2 = csr[e + 2], s3 = csr[e + 3];
            int s4 = csr[e + 4], s5 = csr[e + 5], s6 = csr[e + 6], s7 = csr[e + 7];
            unsigned int v0 = *(const unsigned int*)(Y + (size_t)s0 * 128 + lane2);
            unsigned int v1 = *(const unsigned int*)(Y + (size_t)s1 * 128 + lane2);
            unsigned int v2 = *(const unsigned int*)(Y + (size_t)s2 * 128 + lane2);
            unsigned int v3 = *(const unsigned int*)(Y + (size_t)s3 * 128 + lane2);
            unsigned int v4 = *(const unsigned int*)(Y + (size_t)s4 * 128 + lane2);
            unsigned int v5 = *(const unsigned int*)(Y + (size_t)s5 * 128 + lane2);
            unsigned int v6 = *(const unsigned int*)(Y + (size_t)s6 * 128 + lane2);
            unsigned int v7 = *(const unsigned int*)(Y + (size_t)s7 * 128 + lane2);
            a0 += bflo(v0) + bflo(v1) + bflo(v2) + bflo(v3)
                + bflo(v4) + bflo(v5) + bflo(v6) + bflo(v7);
            a1 += bfhi(v0) + bfhi(v1) + bfhi(v2) + bfhi(v3)
                + bfhi(v4) + bfhi(v5) + bfhi(v6) + bfhi(v7);
        }
        for (; e + 4 <= end; e += 4) {
            int s0 = csr[e + 0], s1 = csr[e + 1], s2 = csr[e + 2], s3 = csr[e + 3];
            unsigned int v0 = *(const unsigned int*)(Y + (size_t)s0 * 128 + lane2);
            unsigned int v1 = *(const unsigned int*)(Y + (size_t)s1 * 128 + lane2);
            unsigned int v2 = *(const unsigned int*)(Y + (size_t)s2 * 128 + lane2);
            unsigned int v3 = *(const unsigned int*)(Y + (size_t)s3 * 128 + lane2);
            a0 += bflo(v0) + bflo(v1) + bflo(v2) + bflo(v3);
            a1 += bfhi(v0) + bfhi(v1) + bfhi(v2) + bfhi(v3);
        }
        for (; e < end; ++e) {
            int s = csr[e];
            unsigned int v = *(const unsigned int*)(Y + (size_t)s * 128 + lane2);
            a0 += bflo(v);
            a1 += bfhi(v);
        }
        unsigned int zv = *(const unsigned int*)(Z + (size_t)n * 128 + lane2);
        float2 bb = *(const float2*)(b + lane2);
        float o0 = a0 * inv + bflo(zv) + bb.x;
        float o1 = a1 * inv + bfhi(zv) + bb.y;
        if (RELU) {
            o0 = o0 > 0.f ? o0 : 0.1f * o0;
            o1 = o1 > 0.f ? o1 : 0.1f * o1;
        }
        unsigned int w = (unsigned int)f2bf(o0) | ((unsigned int)f2bf(o1) << 16);
        *(unsigned int*)(outb + (size_t)n * 128 + lane2) = w;
    } else {
        float a0 = 0.f;
        int e = beg;
        for (; e + 8 <= end; e += 8) {
            int s0 = csr[e + 0], s1 = csr[e + 1], s2 = csr[e + 2], s3 = csr[e + 3];
            int s4 = csr[e + 4], s5 = csr[e + 5], s6 = csr[e + 6], s7 = csr[e + 7];
            float f0 = bf2f(Y[(size_t)s0 * 64 + lane]);
            float f1 = bf2f(Y[(size_t)s1 * 64 + lane]);
            float f2 = bf2f(Y[(size_t)s2 * 64 + lane]);
            float f3 = bf2f(Y[(size_t)s3 * 64 + lane]);
            float f4 = bf2f(Y[(size_t)s4 * 64 + lane]);
            float f5 = bf2f(Y[(size_t)s5 * 64 + lane]);
            float f6 = bf2f(Y[(size_t)s6 * 64 + lane]);
            float f7 = bf2f(Y[(size_t)s7 * 64 + lane]);
            a0 += f0 + f1 + f2 + f3 + f4 + f5 + f6 + f7;
        }
        for (; e + 4 <= end; e += 4) {
            int s0 = csr[e + 0], s1 = csr[e + 1], s2 = csr[e + 2], s3 = csr[e + 3];
            float f0 = bf2f(Y[(size_t)s0 * 64 + lane]);
            float f1 = bf2f(Y[(size_t)s1 * 64 + lane]);
            float f2 = bf2f(Y[(size_t)s2 * 64 + lane]);
            float f3 = bf2f(Y[(size_t)s3 * 64 + lane]);
            a0 += f0 + f1 + f2 + f3;
        }
        for (; e < end; ++e) {
            int s = csr[e];
            a0 += bf2f(Y[(size_t)s * 64 + lane]);
        }
        float o = a0 * inv + bf2f(Z[(size_t)n * 64 + lane]) + b[lane];
        if (RELU) o = o > 0.f ? o : 0.1f * o;
        outf[(size_t)n * 64 + lane] = o;
    }
}

// ---------------- launch ----------------

extern "C" void kernel_launch(void* const* d_in, const int* in_sizes, int n_in,
                              void* d_out, int out_size, void* d_ws, size_t ws_size,
                              hipStream_t stream) {
    const float* x        = (const float*)d_in[0];
    const int*   ei       = (const int*)d_in[1];
    const float* Wl_stack = (const float*)d_in[2];
    const float* Wr_stack = (const float*)d_in[3];
    const float* b_stack  = (const float*)d_in[4];
    const float* Wl_out   = (const float*)d_in[5];
    const float* Wr_out   = (const float*)d_in[6];
    const float* b_out    = (const float*)d_in[7];
    float* out = (float*)d_out;

    unsigned short* xb = (unsigned short*)d_ws;        // [NNP,128]
    unsigned short* hb = xb + (size_t)NNP * 128;       // [NNP,128]
    unsigned short* Yb = hb + (size_t)NNP * 128;       // [NNP,128]
    unsigned short* Zb = Yb + (size_t)NNP * 128;       // [NNP,128]
    unsigned short* WT = Zb + (size_t)NNP * 128;       // 114688 elems
    unsigned long long* ebuf = (unsigned long long*)(WT + 114688);  // [NE], 8B-aligned
    int* row_off = (int*)(ebuf + NE);                  // [NN+1]
    int* csr     = row_off + NN + 1;                   // [NE]
    int* bcnt    = csr + NE;                           // [NBK]
    int* boff    = bcnt + NBK;                         // [NBK+1]
    int* bcur    = boff + NBK + 1;                     // [NBK]

    const int* src = ei;
    const int* dst = ei + NE;

    // bucketed CSR build
    hipMemsetAsync(bcnt, 0, NBK * sizeof(int), stream);
    kb_hist<<<NSC, 256, 0, stream>>>(dst, bcnt);
    kb_scan<<<1, 512, 0, stream>>>(bcnt, boff, bcur);
    kb_scatter<<<NSC, 256, 0, stream>>>(src, dst, bcur, ebuf);
    kb_csr<<<NBK, 256, 0, stream>>>(ebuf, boff, row_off, csr);

    // prep
    k_prep_x<<<(NN * 16 + 255) / 256, 256, 0, stream>>>(x, xb);
    k_prep_wt<<<448, 256, 0, stream>>>(Wl_stack, Wr_stack, Wl_out, Wr_out, WT);

    // layers
    const unsigned short* hin = xb;
    for (int l = 0; l < 3; ++l) {
        k_mm<128><<<NNP / 128, 256, 0, stream>>>(hin, WT + l * 32768, Yb, Zb);
        k_aggb<128, true><<<(NN + 3) / 4, 256, 0, stream>>>(Yb, Zb, row_off, csr,
                                                            b_stack + l * 128, hb, nullptr);
        hin = hb;
    }
    k_mm<64><<<NNP / 128, 256, 0, stream>>>(hin, WT + 98304, Yb, Zb);
    k_aggb<64, false><<<(NN + 3) / 4, 256, 0, stream>>>(Yb, Zb, row_off, csr,
                                                        b_out, nullptr, out);
}

// Round 9
// 440.239 us; speedup vs baseline: 3.2625x; 1.1001x over previous
//
#include <hip/hip_runtime.h>

#define NN 100000
#define NNP 100096            // padded row count (multiple of 128)
#define NE 1600000
#define NBK 391               // node buckets of 256 (dst >> 8)
#define SCCH 4096             // edges per scatter/hist block
#define NSC ((NE + SCCH - 1) / SCCH)   // 391

typedef __attribute__((ext_vector_type(8))) short bf16x8;
typedef __attribute__((ext_vector_type(4))) float f32x4;

__device__ __forceinline__ float bf2f(unsigned short u) {
    unsigned int v = ((unsigned int)u) << 16;
    return __builtin_bit_cast(float, v);
}
__device__ __forceinline__ unsigned short f2bf(float f) {
    unsigned int u = __builtin_bit_cast(unsigned int, f);
    u += 0x7FFFu + ((u >> 16) & 1u);          // RNE
    return (unsigned short)(u >> 16);
}
__device__ __forceinline__ unsigned int pk2(float lo, float hi) {
    return (unsigned int)f2bf(lo) | ((unsigned int)f2bf(hi) << 16);
}
__device__ __forceinline__ float bflo(unsigned int v) {
    return __builtin_bit_cast(float, v << 16);
}
__device__ __forceinline__ float bfhi(unsigned int v) {
    return __builtin_bit_cast(float, v & 0xFFFF0000u);
}

// ---------------- bucketed CSR build ----------------
// bucket = dst >> 8 (256 nodes per bucket, NBK buckets)

__global__ __launch_bounds__(256) void kb_hist(const int* __restrict__ dst,
                                               int* __restrict__ bcnt) {
    __shared__ int lh[NBK];
    int tid = threadIdx.x;
    for (int i = tid; i < NBK; i += 256) lh[i] = 0;
    __syncthreads();
    int base = blockIdx.x * SCCH;
    int lim = min(SCCH, NE - base);
    for (int i = tid; i < lim; i += 256)
        atomicAdd(&lh[dst[base + i] >> 8], 1);
    __syncthreads();
    for (int i = tid; i < NBK; i += 256)
        if (lh[i]) atomicAdd(&bcnt[i], lh[i]);
}

__global__ __launch_bounds__(512) void kb_scan(const int* __restrict__ bcnt,
                                               int* __restrict__ boff,
                                               int* __restrict__ bcur) {
    __shared__ int s[512];
    int tid = threadIdx.x;
    int v = (tid < NBK) ? bcnt[tid] : 0;
    s[tid] = v;
    __syncthreads();
#pragma unroll
    for (int off = 1; off < 512; off <<= 1) {
        int t = (tid >= off) ? s[tid - off] : 0;
        __syncthreads();
        if (tid >= off) s[tid] += t;
        __syncthreads();
    }
    if (tid < NBK) {
        int e = s[tid] - v;       // exclusive
        boff[tid] = e;
        bcur[tid] = e;
    }
    if (tid == 0) boff[NBK] = NE;
}

__global__ __launch_bounds__(256) void kb_scatter(const int* __restrict__ src,
                                                  const int* __restrict__ dst,
                                                  int* __restrict__ bcur,
                                                  unsigned long long* __restrict__ ebuf) {
    __shared__ int lh[NBK], lbase[NBK];
    int tid = threadIdx.x;
    for (int i = tid; i < NBK; i += 256) lh[i] = 0;
    __syncthreads();
    int base = blockIdx.x * SCCH;
    int lim = min(SCCH, NE - base);
    for (int i = tid; i < lim; i += 256)
        atomicAdd(&lh[dst[base + i] >> 8], 1);
    __syncthreads();
    for (int i = tid; i < NBK; i += 256)
        lbase[i] = lh[i] ? atomicAdd(&bcur[i], lh[i]) : 0;
    __syncthreads();
    for (int i = tid; i < NBK; i += 256) lh[i] = 0;
    __syncthreads();
    for (int i = tid; i < lim; i += 256) {
        int d = dst[base + i];
        int s = src[base + i];
        int b = d >> 8;
        int off = atomicAdd(&lh[b], 1);
        ebuf[(size_t)lbase[b] + off] =
            ((unsigned long long)(unsigned)d << 32) | (unsigned)s;
    }
}

__global__ __launch_bounds__(256) void kb_csr(const unsigned long long* __restrict__ ebuf,
                                              const int* __restrict__ boff,
                                              int* __restrict__ row_off,
                                              int* __restrict__ csr) {
    __shared__ int sdeg[256], spre[256];
    int bkt = blockIdx.x;
    int tid = threadIdx.x;
    int nbase = bkt << 8;
    int ebeg = boff[bkt], eend = boff[bkt + 1];
    sdeg[tid] = 0;
    __syncthreads();
    for (int e = ebeg + tid; e < eend; e += 256) {
        int d = (int)(ebuf[e] >> 32);
        atomicAdd(&sdeg[d & 255], 1);
    }
    __syncthreads();
    spre[tid] = sdeg[tid];
    __syncthreads();
#pragma unroll
    for (int off = 1; off < 256; off <<= 1) {
        int t = (tid >= off) ? spre[tid - off] : 0;
        __syncthreads();
        if (tid >= off) spre[tid] += t;
        __syncthreads();
    }
    int excl = spre[tid] - sdeg[tid];
    if (nbase + tid < NN) row_off[nbase + tid] = ebeg + excl;
    if (bkt == 0 && tid == 0) row_off[NN] = NE;
    __syncthreads();
    sdeg[tid] = excl;                 // reuse as cursor
    __syncthreads();
    for (int e = ebeg + tid; e < eend; e += 256) {
        unsigned long long pv = ebuf[e];
        int d = (int)(pv >> 32);
        int s = (int)(unsigned)pv;
        int p = atomicAdd(&sdeg[d & 255], 1);
        csr[ebeg + p] = s;
    }
}

// ---------------- prep: W -> WT bf16 ----------------
// WT layout: layers 0..2: [256][128] each at l*32768; layer 3: [128][128] at 98304

__global__ __launch_bounds__(256) void k_prep_wt(const float* __restrict__ Wl_stack,
                                                 const float* __restrict__ Wr_stack,
                                                 const float* __restrict__ Wl_out,
                                                 const float* __restrict__ Wr_out,
                                                 unsigned short* __restrict__ WT) {
    int i = blockIdx.x * 256 + threadIdx.x;
    const int L3OFF = 3 * 256 * 128;     // 98304
    const int TOT = L3OFF + 128 * 128;   // 114688
    if (i >= TOT) return;
    float v;
    if (i < L3OFF) {
        int l = i / (256 * 128);
        int r = i % (256 * 128);
        int c = r / 128;                 // output col within [Wl|Wr]
        int k = r % 128;
        v = (c < 128) ? Wl_stack[(size_t)(l * 128 + k) * 128 + c]
                      : Wr_stack[(size_t)(l * 128 + k) * 128 + (c - 128)];
    } else {
        int r = i - L3OFF;
        int c = r / 128;
        int k = r % 128;
        v = (c < 64) ? Wl_out[(size_t)k * 64 + c]
                     : Wr_out[(size_t)k * 64 + (c - 64)];
    }
    WT[i] = f2bf(v);
}

// ---------------- MFMA dual GEMM: Y|Z = A @ [Wl|Wr] ----------------
// A: [*,128] bf16 (or fp32 for layer 0, converted in-reg). WT: [N2][128] bf16.
// af loaded ONCE per wave (both row strips); WT streamed from L2.

template <int NOUT, bool F32IN>
__global__ __launch_bounds__(256) void k_mm(const void* __restrict__ Ain,
                                            const unsigned short* __restrict__ WT,
                                            unsigned short* __restrict__ Y,
                                            unsigned short* __restrict__ Z) {
    constexpr int HALVES = NOUT / 64;   // 2 for 128, 1 for 64
    int tid = threadIdx.x;
    int wave = tid >> 6, l = tid & 63;
    int lrow = l & 15, g = l >> 4;
    int rbase = blockIdx.x * 128 + wave * 32;

    bf16x8 af[2][4];
#pragma unroll
    for (int s = 0; s < 2; ++s) {
        int row = rbase + s * 16 + lrow;
#pragma unroll
        for (int ks = 0; ks < 4; ++ks) {
            if (F32IN) {
                int rc = row < NN ? row : NN - 1;   // x is not padded past NN
                const float* ap = (const float*)Ain + (size_t)rc * 128 + ks * 32 + g * 8;
                float4 a = *(const float4*)ap;
                float4 b = *(const float4*)(ap + 4);
                uint4 u;
                u.x = pk2(a.x, a.y); u.y = pk2(a.z, a.w);
                u.z = pk2(b.x, b.y); u.w = pk2(b.z, b.w);
                af[s][ks] = __builtin_bit_cast(bf16x8, u);
            } else {
                af[s][ks] = *(const bf16x8*)((const unsigned short*)Ain
                                             + (size_t)row * 128 + ks * 32 + g * 8);
            }
        }
    }

#pragma unroll
    for (int h = 0; h < HALVES; ++h) {
#pragma unroll
        for (int cg8 = 0; cg8 < 8; ++cg8) {
            int c = (h * 8 + cg8) * 16 + lrow;
            bf16x8 bfr[4];
#pragma unroll
            for (int ks = 0; ks < 4; ++ks)
                bfr[ks] = *(const bf16x8*)(WT + (size_t)c * 128 + ks * 32 + g * 8);
            unsigned short* dstp = (c < NOUT) ? Y : Z;
            int col = (c < NOUT) ? c : c - NOUT;
#pragma unroll
            for (int s = 0; s < 2; ++s) {
                f32x4 acc = {0.f, 0.f, 0.f, 0.f};
#pragma unroll
                for (int ks = 0; ks < 4; ++ks)
                    acc = __builtin_amdgcn_mfma_f32_16x16x32_bf16(af[s][ks], bfr[ks], acc, 0, 0, 0);
                int r0 = rbase + s * 16 + g * 4;
#pragma unroll
                for (int r = 0; r < 4; ++r)
                    dstp[(size_t)(r0 + r) * NOUT + col] = f2bf(acc[r]);
            }
        }
    }
}

// ---------------- aggregation (bf16 gather, scalarized edge stream) ----------------

template <int NOUT, bool RELU>
__global__ __launch_bounds__(256) void k_aggb(const unsigned short* __restrict__ Y,
                                              const unsigned short* __restrict__ Z,
                                              const int* __restrict__ row_off,
                                              const int* __restrict__ csr,
                                              const float* __restrict__ b,
                                              unsigned short* __restrict__ outb,
                                              float* __restrict__ outf) {
    int lane = threadIdx.x & 63;
    // wave-uniform node index forced into SGPRs -> csr loads become scalar (s_load)
    int n = __builtin_amdgcn_readfirstlane(blockIdx.x * 4 + (threadIdx.x >> 6));
    if (n >= NN) return;
    int beg = __builtin_amdgcn_readfirstlane(row_off[n]);
    int end = __builtin_amdgcn_readfirstlane(row_off[n + 1]);
    float inv = (end > beg) ? 1.0f / (float)(end - beg) : 0.0f;

    if (NOUT == 128) {
        const int lane2 = lane * 2;
        float a0 = 0.f, a1 = 0.f;
        int e = beg;
        for (; e + 8 <= end; e += 8) {
            int s0 = csr[e + 0], s1 = csr[e + 1], s2 = csr[e + 2], s3 = csr[e + 3];
            int s4 = csr[e + 4], s5 = csr[e + 5], s6 = csr[e + 6], s7 = csr[e + 7];
            unsigned int v0 = *(const unsigned int*)(Y + (size_t)s0 * 128 + lane2);
            unsigned int v1 = *(const unsigned int*)(Y + (size_t)s1 * 128 + lane2);
            unsigned int v2 = *(const unsigned int*)(Y + (size_t)s2 * 128 + lane2);
            unsigned int v3 = *(const unsigned int*)(Y + (size_t)s3 * 128 + lane2);
            unsigned int v4 = *(const unsigned int*)(Y + (size_t)s4 * 128 + lane2);
            unsigned int v5 = *(const unsigned int*)(Y + (size_t)s5 * 128 + lane2);
            unsigned int v6 = *(const unsigned int*)(Y + (size_t)s6 * 128 + lane2);
            unsigned int v7 = *(const unsigned int*)(Y + (size_t)s7 * 128 + lane2);
            a0 += bflo(v0) + bflo(v1) + bflo(v2) + bflo(v3)
                + bflo(v4) + bflo(v5) + bflo(v6) + bflo(v7);
            a1 += bfhi(v0) + bfhi(v1) + bfhi(v2) + bfhi(v3)
                + bfhi(v4) + bfhi(v5) + bfhi(v6) + bfhi(v7);
        }
        for (; e + 4 <= end; e += 4) {
            int s0 = csr[e + 0], s1 = csr[e + 1], s2 = csr[e + 2], s3 = csr[e + 3];
            unsigned int v0 = *(const unsigned int*)(Y + (size_t)s0 * 128 + lane2);
            unsigned int v1 = *(const unsigned int*)(Y + (size_t)s1 * 128 + lane2);
            unsigned int v2 = *(const unsigned int*)(Y + (size_t)s2 * 128 + lane2);
            unsigned int v3 = *(const unsigned int*)(Y + (size_t)s3 * 128 + lane2);
            a0 += bflo(v0) + bflo(v1) + bflo(v2) + bflo(v3);
            a1 += bfhi(v0) + bfhi(v1) + bfhi(v2) + bfhi(v3);
        }
        for (; e < end; ++e) {
            int s = csr[e];
            unsigned int v = *(const unsigned int*)(Y + (size_t)s * 128 + lane2);
            a0 += bflo(v);
            a1 += bfhi(v);
        }
        unsigned int zv = *(const unsigned int*)(Z + (size_t)n * 128 + lane2);
        float2 bb = *(const float2*)(b + lane2);
        float o0 = a0 * inv + bflo(zv) + bb.x;
        float o1 = a1 * inv + bfhi(zv) + bb.y;
        if (RELU) {
            o0 = o0 > 0.f ? o0 : 0.1f * o0;
            o1 = o1 > 0.f ? o1 : 0.1f * o1;
        }
        *(unsigned int*)(outb + (size_t)n * 128 + lane2) = pk2(o0, o1);
    } else {
        float a0 = 0.f;
        int e = beg;
        for (; e + 8 <= end; e += 8) {
            int s0 = csr[e + 0], s1 = csr[e + 1], s2 = csr[e + 2], s3 = csr[e + 3];
            int s4 = csr[e + 4], s5 = csr[e + 5], s6 = csr[e + 6], s7 = csr[e + 7];
            float f0 = bf2f(Y[(size_t)s0 * 64 + lane]);
            float f1 = bf2f(Y[(size_t)s1 * 64 + lane]);
            float f2 = bf2f(Y[(size_t)s2 * 64 + lane]);
            float f3 = bf2f(Y[(size_t)s3 * 64 + lane]);
            float f4 = bf2f(Y[(size_t)s4 * 64 + lane]);
            float f5 = bf2f(Y[(size_t)s5 * 64 + lane]);
            float f6 = bf2f(Y[(size_t)s6 * 64 + lane]);
            float f7 = bf2f(Y[(size_t)s7 * 64 + lane]);
            a0 += f0 + f1 + f2 + f3 + f4 + f5 + f6 + f7;
        }
        for (; e + 4 <= end; e += 4) {
            int s0 = csr[e + 0], s1 = csr[e + 1], s2 = csr[e + 2], s3 = csr[e + 3];
            float f0 = bf2f(Y[(size_t)s0 * 64 + lane]);
            float f1 = bf2f(Y[(size_t)s1 * 64 + lane]);
            float f2 = bf2f(Y[(size_t)s2 * 64 + lane]);
            float f3 = bf2f(Y[(size_t)s3 * 64 + lane]);
            a0 += f0 + f1 + f2 + f3;
        }
        for (; e < end; ++e) {
            int s = csr[e];
            a0 += bf2f(Y[(size_t)s * 64 + lane]);
        }
        float o = a0 * inv + bf2f(Z[(size_t)n * 64 + lane]) + b[lane];
        if (RELU) o = o > 0.f ? o : 0.1f * o;
        outf[(size_t)n * 64 + lane] = o;
    }
}

// ---------------- launch ----------------

extern "C" void kernel_launch(void* const* d_in, const int* in_sizes, int n_in,
                              void* d_out, int out_size, void* d_ws, size_t ws_size,
                              hipStream_t stream) {
    const float* x        = (const float*)d_in[0];
    const int*   ei       = (const int*)d_in[1];
    const float* Wl_stack = (const float*)d_in[2];
    const float* Wr_stack = (const float*)d_in[3];
    const float* b_stack  = (const float*)d_in[4];
    const float* Wl_out   = (const float*)d_in[5];
    const float* Wr_out   = (const float*)d_in[6];
    const float* b_out    = (const float*)d_in[7];
    float* out = (float*)d_out;

    unsigned short* hb = (unsigned short*)d_ws;        // [NNP,128]
    unsigned short* Yb = hb + (size_t)NNP * 128;       // [NNP,128]
    unsigned short* Zb = Yb + (size_t)NNP * 128;       // [NNP,128]
    unsigned short* WT = Zb + (size_t)NNP * 128;       // 114688 elems
    unsigned long long* ebuf = (unsigned long long*)(WT + 114688);  // [NE]
    int* row_off = (int*)(ebuf + NE);                  // [NN+1]
    int* csr     = row_off + NN + 1;                   // [NE]
    int* bcnt    = csr + NE;                           // [NBK]
    int* boff    = bcnt + NBK;                         // [NBK+1]
    int* bcur    = boff + NBK + 1;                     // [NBK]

    const int* src = ei;
    const int* dst = ei + NE;

    // bucketed CSR build
    (void)hipMemsetAsync(bcnt, 0, NBK * sizeof(int), stream);
    kb_hist<<<NSC, 256, 0, stream>>>(dst, bcnt);
    kb_scan<<<1, 512, 0, stream>>>(bcnt, boff, bcur);
    kb_scatter<<<NSC, 256, 0, stream>>>(src, dst, bcur, ebuf);
    kb_csr<<<NBK, 256, 0, stream>>>(ebuf, boff, row_off, csr);

    // weights -> bf16 transposed
    k_prep_wt<<<448, 256, 0, stream>>>(Wl_stack, Wr_stack, Wl_out, Wr_out, WT);

    // layer 0 (fp32 x read directly, converted in-register)
    k_mm<128, true><<<NNP / 128, 256, 0, stream>>>(x, WT, Yb, Zb);
    k_aggb<128, true><<<(NN + 3) / 4, 256, 0, stream>>>(Yb, Zb, row_off, csr,
                                                        b_stack, hb, nullptr);
    // layers 1..2
    for (int l = 1; l < 3; ++l) {
        k_mm<128, false><<<NNP / 128, 256, 0, stream>>>(hb, WT + l * 32768, Yb, Zb);
        k_aggb<128, true><<<(NN + 3) / 4, 256, 0, stream>>>(Yb, Zb, row_off, csr,
                                                            b_stack + l * 128, hb, nullptr);
    }
    // final layer
    k_mm<64, false><<<NNP / 128, 256, 0, stream>>>(hb, WT + 98304, Yb, Zb);
    k_aggb<64, false><<<(NN + 3) / 4, 256, 0, stream>>>(Yb, Zb, row_off, csr,
                                                        b_out, nullptr, out);
}